// Round 9
// baseline (45.238 us; speedup 1.0000x reference)
//
#include <hip/hip_runtime.h>

#define SCALE 0.35355339059327379f   // 8^-0.5
#define RSQRT2 0.70710678118654752f

// ws layout (float offsets)
#define PL      4624                 // 68*68 padded plane
#define QP_OFF  0                    // qP[64 ic][68][68]
#define KP_OFF  (64*PL)
#define VP_OFF  (2*64*PL)            // Vpart [4 p][64 x][64 ch]
#define WP_OFF  (VP_OFF + 4*4096)    // wPad [2 type][64 oc][64 ic][11 kh][12]
#define WP_SZ   (2*64*64*132)
#define QD_OFF  (WP_OFF + WP_SZ)     // qd [oc][il] post-GELU
#define KD_OFF  (QD_OFF + 4096)

// ---------------- K1: blocks 0..127: 1x1 qkv conv -> planar padded q/k planes + Vpart.
//                  blocks 128..255: weight repack wq/wk -> wPad[type][oc][ic][kh][12].
__global__ __launch_bounds__(384) void k1(const float* __restrict__ f,
                                          const float* __restrict__ w_qkv,
                                          const float* __restrict__ wq,
                                          const float* __restrict__ wk,
                                          float* __restrict__ ws)
{
    __shared__ float sm[14656];      // compute: wt[64][193] @0, fl[64][36] @12352 ; repack: wl[7744]
    const int b = blockIdx.x, t = threadIdx.x;

    if (b >= 128) {
        // ---- weight repack block: rb = (type, oc) ----
        const int rb = b - 128;
        const int type = rb >> 6, oc = rb & 63;
        const float* wsrc = (type ? wk : wq) + oc*7744;
        float* wdst = ws + WP_OFF + (size_t)(type*64 + oc)*64*132;
        float* wl = sm;
        #pragma unroll
        for (int j = 0; j < 6; ++j) {
            const int idx = t + 384*j;            // float4 idx in [0,1936)
            if (idx < 1936)
                *(float4*)&wl[4*idx] = *(const float4*)(wsrc + 4*idx);
        }
        __syncthreads();
        for (int p = t; p < 704; p += 384) {      // 64 ic x 11 kh
            const int ic = p / 11, kh = p % 11;
            const float* s = &wl[ic*121 + kh*11];
            float* d = &wdst[ic*132 + kh*12];
            #pragma unroll
            for (int kw = 0; kw < 11; ++kw) d[kw] = s[kw];
        }
        return;
    }

    // ---- compute block: x row, y-half ----
    const int x = b >> 1, yh = b & 1;
    float* wt = sm;
    float* fl = sm + 12352;

    // zero pad borders: block (x,0) -> qP plane x ; (x,1) -> kP plane x
    {
        float* plane = ws + (yh ? KP_OFF : QP_OFF) + x*PL;
        for (int j = t; j < 528; j += 384) {
            int idx;
            if (j < 272) {
                const int rp = j / 68, c = j % 68;
                const int row = (rp < 2) ? rp : rp + 64;
                idx = row*68 + c;
            } else {
                const int jj = j - 272;
                const int cp = jj >> 6, r2 = (jj & 63) + 2;
                const int col = (cp < 2) ? cp : cp + 64;
                idx = r2*68 + col;
            }
            plane[idx] = 0.f;
        }
    }
    // stage w_qkv transposed: wt[ic][3*64 oc]
    #pragma unroll
    for (int j = 0; j < 8; ++j) {
        const int idx = t + 384*j;   // float4 idx in [0,3072)
        const float4 v = *(const float4*)(w_qkv + 4*idx);
        const int oc = idx >> 4, ic0 = (4*idx) & 63;
        wt[(ic0+0)*193 + oc] = v.x;
        wt[(ic0+1)*193 + oc] = v.y;
        wt[(ic0+2)*193 + oc] = v.z;
        wt[(ic0+3)*193 + oc] = v.w;
    }
    // stage f slab [64 ic][32 y]
    for (int i = t; i < 512; i += 384) {
        const int ic = i >> 3, p = i & 7;
        *(float4*)&fl[ic*36 + p*4] = *(const float4*)(f + ic*4096 + x*64 + yh*32 + p*4);
    }
    __syncthreads();

    const int w = t >> 6, lane = t & 63;
    const int type = w >> 1, yoct = w & 1;
    float acc[16];
    #pragma unroll
    for (int j = 0; j < 16; ++j) acc[j] = 0.f;
    #pragma unroll 4
    for (int ic = 0; ic < 64; ++ic) {
        const float wv = wt[ic*193 + type*64 + lane];
        const float4 p0 = *(const float4*)&fl[ic*36 + yoct*16];
        const float4 p1 = *(const float4*)&fl[ic*36 + yoct*16 + 4];
        const float4 p2 = *(const float4*)&fl[ic*36 + yoct*16 + 8];
        const float4 p3 = *(const float4*)&fl[ic*36 + yoct*16 + 12];
        acc[0]  = fmaf(wv, p0.x, acc[0]);  acc[1]  = fmaf(wv, p0.y, acc[1]);
        acc[2]  = fmaf(wv, p0.z, acc[2]);  acc[3]  = fmaf(wv, p0.w, acc[3]);
        acc[4]  = fmaf(wv, p1.x, acc[4]);  acc[5]  = fmaf(wv, p1.y, acc[5]);
        acc[6]  = fmaf(wv, p1.z, acc[6]);  acc[7]  = fmaf(wv, p1.w, acc[7]);
        acc[8]  = fmaf(wv, p2.x, acc[8]);  acc[9]  = fmaf(wv, p2.y, acc[9]);
        acc[10] = fmaf(wv, p2.z, acc[10]); acc[11] = fmaf(wv, p2.w, acc[11]);
        acc[12] = fmaf(wv, p3.x, acc[12]); acc[13] = fmaf(wv, p3.y, acc[13]);
        acc[14] = fmaf(wv, p3.z, acc[14]); acc[15] = fmaf(wv, p3.w, acc[15]);
    }
    if (type < 2) {
        float* plane = ws + (type ? KP_OFF : QP_OFF) + lane*PL;
        const int base = (x + 2)*68 + yh*32 + yoct*16 + 2;
        #pragma unroll
        for (int j = 0; j < 8; ++j)
            *(float2*)(plane + base + 2*j) = make_float2(acc[2*j], acc[2*j+1]);
    } else {
        float s = 0.f;
        #pragma unroll
        for (int j = 0; j < 16; ++j) s += acc[j];
        (ws + VP_OFF)[(yh*2 + yoct)*4096 + x*64 + lane] = s * 0.015625f;  // /64 partial
    }
}

// ---------------- K2: output-split 11x11 s8 conv, complete outputs in-block.
// grid 256 = (type, ox, ocg of 4 oc). 512 thr: t = (oc2:2)(ick:4)(oy:3).
// Each thread: partial over 4 ic (ick, ick+16, +32, +48), all 121 taps.
// In-block 16-way LDS reduce -> bias -> exact GELU -> final qd/kd store.
__global__ __launch_bounds__(512) void k2(const float* __restrict__ ws_qP,
                                          const float* __restrict__ ws_kP,
                                          const float* __restrict__ wPad,
                                          const float* __restrict__ bq,
                                          const float* __restrict__ bk,
                                          float* __restrict__ qd,
                                          float* __restrict__ kd)
{
    __shared__ float red[512];
    const int b = blockIdx.x, t = threadIdx.x;
    const int type = b >> 7, ox = (b >> 4) & 7, ocg = b & 15;
    const float* planes = type ? ws_kP : ws_qP;
    const int oc2 = t >> 7, ick = (t >> 3) & 15, oy = t & 7;
    const int oc = ocg*4 + oc2;
    const float* wbase = wPad + (size_t)(type*64 + oc)*64*132;

    float a0 = 0.f, a1 = 0.f;
    for (int j = 0; j < 4; ++j) {
        const int ic = ick + 16*j;
        const float* pl = planes + ic*PL + (ox*8)*68 + oy*8;
        const float* wr = wbase + ic*132;
        #pragma unroll
        for (int kh = 0; kh < 11; ++kh) {
            const float4 r0 = *(const float4*)(pl + kh*68);
            const float4 r1 = *(const float4*)(pl + kh*68 + 4);
            const float4 r2 = *(const float4*)(pl + kh*68 + 8);
            const float4 w0 = *(const float4*)(wr + kh*12);
            const float4 w1 = *(const float4*)(wr + kh*12 + 4);
            const float4 w2 = *(const float4*)(wr + kh*12 + 8);
            a0 = fmaf(w0.x, r0.x, a0); a1 = fmaf(w0.y, r0.y, a1);
            a0 = fmaf(w0.z, r0.z, a0); a1 = fmaf(w0.w, r0.w, a1);
            a0 = fmaf(w1.x, r1.x, a0); a1 = fmaf(w1.y, r1.y, a1);
            a0 = fmaf(w1.z, r1.z, a0); a1 = fmaf(w1.w, r1.w, a1);
            a0 = fmaf(w2.x, r2.x, a0); a1 = fmaf(w2.y, r2.y, a1);
            a0 = fmaf(w2.z, r2.z, a0);                       // 11 taps (col oy*8+11 loaded, unused)
        }
    }
    red[t] = a0 + a1;
    __syncthreads();
    if (t < 32) {
        const int ro = t >> 3, ry = t & 7;      // ro = oc2, ry = oy
        float s = 0.f;
        #pragma unroll
        for (int k = 0; k < 16; ++k) s += red[ro*128 + k*8 + ry];
        const int occ = ocg*4 + ro;
        const float v = s + (type ? bk[occ] : bq[occ]);
        (type ? kd : qd)[occ*64 + ox*8 + ry] = 0.5f*v*(1.0f + erff(v*RSQRT2));
    }
}

// ---------------- K3: Vpart-reduce prologue + dots + softmax + PV ----------------
// grid 64 (x = image row), 512 thr: wave = head, lane = jl.
__global__ __launch_bounds__(512) void k3(const float* __restrict__ qd,
                                          const float* __restrict__ kd,
                                          const float* __restrict__ Vpart,
                                          float* __restrict__ out)
{
    __shared__ float vrow[64*65];     // [ch][jl], pitch 65
    const int x = blockIdx.x, t = threadIdx.x;
    for (int idx = t; idx < 4096; idx += 512) {
        const int jl = idx >> 6, ch = idx & 63;
        float s = 0.f;
        #pragma unroll
        for (int p = 0; p < 4; ++p) s += Vpart[p*4096 + jl*64 + ch];
        vrow[ch*65 + jl] = s;
    }
    __syncthreads();
    const int h = t >> 6, lane = t & 63;
    float d = 0.f;
    #pragma unroll
    for (int c = 0; c < 8; ++c)
        d = fmaf(qd[(h*8 + c)*64 + x], kd[(h*8 + c)*64 + lane], d);
    d *= SCALE;
    float m = d;
    #pragma unroll
    for (int mm = 1; mm < 64; mm <<= 1) m = fmaxf(m, __shfl_xor(m, mm, 64));
    const float e = __expf(d - m);
    float ssum = e;
    #pragma unroll
    for (int mm = 1; mm < 64; mm <<= 1) ssum += __shfl_xor(ssum, mm, 64);
    const float p = e / ssum;
    #pragma unroll
    for (int c = 0; c < 8; ++c) {
        float r = p * vrow[(h*8 + c)*65 + lane];
        #pragma unroll
        for (int mm = 1; mm < 64; mm <<= 1) r += __shfl_xor(r, mm, 64);
        out[(h*8 + c)*4096 + x*64 + lane] = r;
    }
}

extern "C" void kernel_launch(void* const* d_in, const int* in_sizes, int n_in,
                              void* d_out, int out_size, void* d_ws, size_t ws_size,
                              hipStream_t stream) {
    const float* f     = (const float*)d_in[0];
    const float* w_qkv = (const float*)d_in[1];
    const float* wq    = (const float*)d_in[2];
    const float* bq    = (const float*)d_in[3];
    const float* wk    = (const float*)d_in[4];
    const float* bk    = (const float*)d_in[5];
    float* out = (float*)d_out;
    float* ws  = (float*)d_ws;

    k1<<<256, 384, 0, stream>>>(f, w_qkv, wq, wk, ws);
    k2<<<256, 512, 0, stream>>>(ws + QP_OFF, ws + KP_OFF, ws + WP_OFF,
                                bq, bk, ws + QD_OFF, ws + KD_OFF);
    k3<<<64, 512, 0, stream>>>(ws + QD_OFF, ws + KD_OFF, ws + VP_OFF, out);
}

// Round 10
// 44.806 us; speedup vs baseline: 1.0097x; 1.0097x over previous
//
#include <hip/hip_runtime.h>

#define SCALE 0.35355339059327379f   // 8^-0.5
#define RSQRT2 0.70710678118654752f

// ws layout (float offsets)
#define PL      4624                 // 68*68 padded plane
#define QP_OFF  0                    // qP[64 ic][68][68]
#define KP_OFF  (64*PL)
#define PART_OFF (2*64*PL)           // part[256 pid][64 oc][64 il]  (pid = type*128+ic*2+khh)
#define VP_OFF  (PART_OFF + 256*4096)// Vpart [4 p][64 x][64 ch]

// ---------------- K1: 1x1 qkv conv -> planar padded q/k planes + V row-mean partials ----
// grid 128: (x = b>>1, yh = b&1), 384 thr = 6 waves: (type q/k/v) x (y-oct), lane = oc.
__global__ __launch_bounds__(384) void k1(const float* __restrict__ f,
                                          const float* __restrict__ w_qkv,
                                          float* __restrict__ ws)
{
    __shared__ float sm[14656];      // wt[64][193] @0 ; fl[64][36] @12352
    const int b = blockIdx.x, t = threadIdx.x;
    const int x = b >> 1, yh = b & 1;
    float* wt = sm;
    float* fl = sm + 12352;

    // zero pad borders: block (x,0) -> qP plane x ; (x,1) -> kP plane x
    {
        float* plane = ws + (yh ? KP_OFF : QP_OFF) + x*PL;
        for (int j = t; j < 528; j += 384) {
            int idx;
            if (j < 272) {
                const int rp = j / 68, c = j % 68;
                const int row = (rp < 2) ? rp : rp + 64;
                idx = row*68 + c;
            } else {
                const int jj = j - 272;
                const int cp = jj >> 6, r2 = (jj & 63) + 2;
                const int col = (cp < 2) ? cp : cp + 64;
                idx = r2*68 + col;
            }
            plane[idx] = 0.f;
        }
    }
    // stage w_qkv transposed: wt[ic][3*64 oc]
    #pragma unroll
    for (int j = 0; j < 8; ++j) {
        const int idx = t + 384*j;   // float4 idx in [0,3072)
        const float4 v = *(const float4*)(w_qkv + 4*idx);
        const int oc = idx >> 4, ic0 = (4*idx) & 63;
        wt[(ic0+0)*193 + oc] = v.x;
        wt[(ic0+1)*193 + oc] = v.y;
        wt[(ic0+2)*193 + oc] = v.z;
        wt[(ic0+3)*193 + oc] = v.w;
    }
    // stage f slab [64 ic][32 y]
    for (int i = t; i < 512; i += 384) {
        const int ic = i >> 3, p = i & 7;
        *(float4*)&fl[ic*36 + p*4] = *(const float4*)(f + ic*4096 + x*64 + yh*32 + p*4);
    }
    __syncthreads();

    const int w = t >> 6, lane = t & 63;
    const int type = w >> 1, yoct = w & 1;
    float acc[16];
    #pragma unroll
    for (int j = 0; j < 16; ++j) acc[j] = 0.f;
    #pragma unroll 4
    for (int ic = 0; ic < 64; ++ic) {
        const float wv = wt[ic*193 + type*64 + lane];
        const float4 p0 = *(const float4*)&fl[ic*36 + yoct*16];
        const float4 p1 = *(const float4*)&fl[ic*36 + yoct*16 + 4];
        const float4 p2 = *(const float4*)&fl[ic*36 + yoct*16 + 8];
        const float4 p3 = *(const float4*)&fl[ic*36 + yoct*16 + 12];
        acc[0]  = fmaf(wv, p0.x, acc[0]);  acc[1]  = fmaf(wv, p0.y, acc[1]);
        acc[2]  = fmaf(wv, p0.z, acc[2]);  acc[3]  = fmaf(wv, p0.w, acc[3]);
        acc[4]  = fmaf(wv, p1.x, acc[4]);  acc[5]  = fmaf(wv, p1.y, acc[5]);
        acc[6]  = fmaf(wv, p1.z, acc[6]);  acc[7]  = fmaf(wv, p1.w, acc[7]);
        acc[8]  = fmaf(wv, p2.x, acc[8]);  acc[9]  = fmaf(wv, p2.y, acc[9]);
        acc[10] = fmaf(wv, p2.z, acc[10]); acc[11] = fmaf(wv, p2.w, acc[11]);
        acc[12] = fmaf(wv, p3.x, acc[12]); acc[13] = fmaf(wv, p3.y, acc[13]);
        acc[14] = fmaf(wv, p3.z, acc[14]); acc[15] = fmaf(wv, p3.w, acc[15]);
    }
    if (type < 2) {
        float* plane = ws + (type ? KP_OFF : QP_OFF) + lane*PL;
        const int base = (x + 2)*68 + yh*32 + yoct*16 + 2;
        #pragma unroll
        for (int j = 0; j < 8; ++j)
            *(float2*)(plane + base + 2*j) = make_float2(acc[2*j], acc[2*j+1]);
    } else {
        float s = 0.f;
        #pragma unroll
        for (int j = 0; j < 16; ++j) s += acc[j];
        (ws + VP_OFF)[(yh*2 + yoct)*4096 + x*64 + lane] = s * 0.015625f;  // /64 partial
    }
}

// ---------------- K2: 11x11 s8 conv as K-split GEMM. grid 256: (type, ic, khh).
// 512 thr, lane = il (output pos), wave = oc-eighth. No LDS, no barriers.
// Plane window -> registers (L1-shared across waves); weights -> wave-uniform scalar loads.
__global__ __launch_bounds__(512) void k2(const float* __restrict__ ws_qP,
                                          const float* __restrict__ ws_kP,
                                          const float* __restrict__ wq,
                                          const float* __restrict__ wk,
                                          float* __restrict__ part)
{
    const int b = blockIdx.x, t = threadIdx.x;
    const int type = b >> 7, ic = (b >> 1) & 63, khh = b & 1;
    const int kh0 = khh ? 6 : 0, nkh = khh ? 5 : 6;
    const float* plane = (type ? ws_kP : ws_qP) + ic*PL;
    const float* wsrc  = (type ? wk : wq) + ic*121 + kh0*11;
    const int lane = t & 63;
    const int oc0 = __builtin_amdgcn_readfirstlane(t >> 6) * 8;   // wave-uniform
    const int ox = lane >> 3, oy = lane & 7;

    float acc[8] = {0.f,0.f,0.f,0.f,0.f,0.f,0.f,0.f};
    #pragma unroll
    for (int khl = 0; khl < 6; ++khl) {
        if (khl < nkh) {
            const int xp = ox*8 + kh0 + khl;
            const float* prow = plane + xp*68 + oy*8;     // 16B-aligned
            const float4 r0 = *(const float4*)(prow);
            const float4 r1 = *(const float4*)(prow + 4);
            const float4 r2 = *(const float4*)(prow + 8);
            const float pr[12] = {r0.x,r0.y,r0.z,r0.w, r1.x,r1.y,r1.z,r1.w,
                                  r2.x,r2.y,r2.z,r2.w};
            const float* wrow = wsrc + khl*11;
            #pragma unroll
            for (int kw = 0; kw < 11; ++kw) {
                const float pv = pr[kw];
                #pragma unroll
                for (int j = 0; j < 8; ++j) {
                    const float wgt = wrow[(oc0 + j)*7744 + kw];  // uniform -> s_load
                    acc[j] = fmaf(wgt, pv, acc[j]);
                }
            }
        }
    }
    // partial store: part[b][oc][il]   (pid == b by construction)
    float* pp = part + (size_t)b*4096 + lane;
    #pragma unroll
    for (int j = 0; j < 8; ++j) pp[(oc0 + j)*64] = acc[j];
}

// ---------------- K3: fused {partial reduce + bias + GELU} + dots + softmax + PV ------
// grid 64 = (h = b>>3, xo = b&7). 512 thr.
// Phase A: reduce this head's kd slice (coalesced: wave = c row, lane = jl),
//          qd for its 8 rows, vrow slice; bias + exact GELU in-block.
// Phase B: wave w -> query row x = xo*8+w; lane = jl; softmax + PV + broadcast store.
__global__ __launch_bounds__(512) void k3(const float* __restrict__ part,
                                          const float* __restrict__ Vpart,
                                          const float* __restrict__ bq,
                                          const float* __restrict__ bk,
                                          float* __restrict__ out)
{
    __shared__ float kg[512];   // [c][jl]
    __shared__ float vr[512];   // [c][jl]
    __shared__ float qg[64];    // [c][xl]
    const int b = blockIdx.x, t = threadIdx.x;
    const int h = b >> 3, xo = b & 7;
    const int c = t >> 6, jl = t & 63;
    const int oc = h*8 + c;

    // kd slice reduce (128 partials, pids 128..255), coalesced per wave
    {
        float s = 0.f;
        const float* pp = part + (size_t)128*4096 + oc*64 + jl;
        #pragma unroll 8
        for (int p = 0; p < 128; ++p) s += pp[(size_t)p*4096];
        const float v = s + bk[oc];
        kg[c*64 + jl] = 0.5f*v*(1.0f + erff(v*RSQRT2));
    }
    // vrow slice
    {
        float s = 0.f;
        #pragma unroll
        for (int p = 0; p < 4; ++p) s += Vpart[p*4096 + jl*64 + oc];
        vr[c*64 + jl] = s;
    }
    // qd for this block's 8 query rows (threads 0..63)
    if (t < 64) {
        const int cc = t >> 3, xl = t & 7;
        const int qoc = h*8 + cc;
        const int il = xo*8 + xl;
        float s = 0.f;
        const float* pp = part + qoc*64 + il;
        #pragma unroll 8
        for (int p = 0; p < 128; ++p) s += pp[(size_t)p*4096];
        const float v = s + bq[qoc];
        qg[cc*8 + xl] = 0.5f*v*(1.0f + erff(v*RSQRT2));
    }
    __syncthreads();

    const int w = t >> 6, lane = t & 63;   // wave w -> x = xo*8 + w
    float d = 0.f;
    #pragma unroll
    for (int cc = 0; cc < 8; ++cc)
        d = fmaf(qg[cc*8 + w], kg[cc*64 + lane], d);
    d *= SCALE;
    float m = d;
    #pragma unroll
    for (int mm = 1; mm < 64; mm <<= 1) m = fmaxf(m, __shfl_xor(m, mm, 64));
    const float e = __expf(d - m);
    float ssum = e;
    #pragma unroll
    for (int mm = 1; mm < 64; mm <<= 1) ssum += __shfl_xor(ssum, mm, 64);
    const float p = e / ssum;
    const int x = xo*8 + w;
    #pragma unroll
    for (int cc = 0; cc < 8; ++cc) {
        float r = p * vr[cc*64 + lane];
        #pragma unroll
        for (int mm = 1; mm < 64; mm <<= 1) r += __shfl_xor(r, mm, 64);
        out[(h*8 + cc)*4096 + x*64 + lane] = r;
    }
}

extern "C" void kernel_launch(void* const* d_in, const int* in_sizes, int n_in,
                              void* d_out, int out_size, void* d_ws, size_t ws_size,
                              hipStream_t stream) {
    const float* f     = (const float*)d_in[0];
    const float* w_qkv = (const float*)d_in[1];
    const float* wq    = (const float*)d_in[2];
    const float* bq    = (const float*)d_in[3];
    const float* wk    = (const float*)d_in[4];
    const float* bk    = (const float*)d_in[5];
    float* out = (float*)d_out;
    float* ws  = (float*)d_ws;

    k1<<<128, 384, 0, stream>>>(f, w_qkv, ws);
    k2<<<256, 512, 0, stream>>>(ws + QP_OFF, ws + KP_OFF, wq, wk, ws + PART_OFF);
    k3<<<64, 512, 0, stream>>>(ws + PART_OFF, ws + VP_OFF, bq, bk, out);
}

// Round 11
// 35.169 us; speedup vs baseline: 1.2863x; 1.2740x over previous
//
#include <hip/hip_runtime.h>

#define SCALE 0.35355339059327379f   // 8^-0.5
#define RSQRT2 0.70710678118654752f

// ws layout (float offsets)
#define PL      4624                 // 68*68 padded plane
#define QP_OFF  0                    // qP[64 ic][68][68]
#define KP_OFF  (64*PL)
#define PART_OFF (2*64*PL)           // part[256 pid][64 oc][64 il]  (pid = type*128+ic*2+khh)
#define VP_OFF  (PART_OFF + 256*4096)// Vpart [4 p][64 x][64 ch]

// ---------------- K1: 1x1 qkv conv -> planar padded q/k planes + V row-mean partials ----
// grid 128: (x = b>>1, yh = b&1), 384 thr = 6 waves: (type q/k/v) x (y-oct), lane = oc.
__global__ __launch_bounds__(384) void k1(const float* __restrict__ f,
                                          const float* __restrict__ w_qkv,
                                          float* __restrict__ ws)
{
    __shared__ float sm[14656];      // wt[64][193] @0 ; fl[64][36] @12352
    const int b = blockIdx.x, t = threadIdx.x;
    const int x = b >> 1, yh = b & 1;
    float* wt = sm;
    float* fl = sm + 12352;

    // zero pad borders: block (x,0) -> qP plane x ; (x,1) -> kP plane x
    {
        float* plane = ws + (yh ? KP_OFF : QP_OFF) + x*PL;
        for (int j = t; j < 528; j += 384) {
            int idx;
            if (j < 272) {
                const int rp = j / 68, c = j % 68;
                const int row = (rp < 2) ? rp : rp + 64;
                idx = row*68 + c;
            } else {
                const int jj = j - 272;
                const int cp = jj >> 6, r2 = (jj & 63) + 2;
                const int col = (cp < 2) ? cp : cp + 64;
                idx = r2*68 + col;
            }
            plane[idx] = 0.f;
        }
    }
    // stage w_qkv transposed: wt[ic][3*64 oc]
    #pragma unroll
    for (int j = 0; j < 8; ++j) {
        const int idx = t + 384*j;   // float4 idx in [0,3072)
        const float4 v = *(const float4*)(w_qkv + 4*idx);
        const int oc = idx >> 4, ic0 = (4*idx) & 63;
        wt[(ic0+0)*193 + oc] = v.x;
        wt[(ic0+1)*193 + oc] = v.y;
        wt[(ic0+2)*193 + oc] = v.z;
        wt[(ic0+3)*193 + oc] = v.w;
    }
    // stage f slab [64 ic][32 y]
    for (int i = t; i < 512; i += 384) {
        const int ic = i >> 3, p = i & 7;
        *(float4*)&fl[ic*36 + p*4] = *(const float4*)(f + ic*4096 + x*64 + yh*32 + p*4);
    }
    __syncthreads();

    const int w = t >> 6, lane = t & 63;
    const int type = w >> 1, yoct = w & 1;
    float acc[16];
    #pragma unroll
    for (int j = 0; j < 16; ++j) acc[j] = 0.f;
    #pragma unroll 4
    for (int ic = 0; ic < 64; ++ic) {
        const float wv = wt[ic*193 + type*64 + lane];
        const float4 p0 = *(const float4*)&fl[ic*36 + yoct*16];
        const float4 p1 = *(const float4*)&fl[ic*36 + yoct*16 + 4];
        const float4 p2 = *(const float4*)&fl[ic*36 + yoct*16 + 8];
        const float4 p3 = *(const float4*)&fl[ic*36 + yoct*16 + 12];
        acc[0]  = fmaf(wv, p0.x, acc[0]);  acc[1]  = fmaf(wv, p0.y, acc[1]);
        acc[2]  = fmaf(wv, p0.z, acc[2]);  acc[3]  = fmaf(wv, p0.w, acc[3]);
        acc[4]  = fmaf(wv, p1.x, acc[4]);  acc[5]  = fmaf(wv, p1.y, acc[5]);
        acc[6]  = fmaf(wv, p1.z, acc[6]);  acc[7]  = fmaf(wv, p1.w, acc[7]);
        acc[8]  = fmaf(wv, p2.x, acc[8]);  acc[9]  = fmaf(wv, p2.y, acc[9]);
        acc[10] = fmaf(wv, p2.z, acc[10]); acc[11] = fmaf(wv, p2.w, acc[11]);
        acc[12] = fmaf(wv, p3.x, acc[12]); acc[13] = fmaf(wv, p3.y, acc[13]);
        acc[14] = fmaf(wv, p3.z, acc[14]); acc[15] = fmaf(wv, p3.w, acc[15]);
    }
    if (type < 2) {
        float* plane = ws + (type ? KP_OFF : QP_OFF) + lane*PL;
        const int base = (x + 2)*68 + yh*32 + yoct*16 + 2;
        #pragma unroll
        for (int j = 0; j < 8; ++j)
            *(float2*)(plane + base + 2*j) = make_float2(acc[2*j], acc[2*j+1]);
    } else {
        float s = 0.f;
        #pragma unroll
        for (int j = 0; j < 16; ++j) s += acc[j];
        (ws + VP_OFF)[(yh*2 + yoct)*4096 + x*64 + lane] = s * 0.015625f;  // /64 partial
    }
}

// ---------------- K2: 11x11 s8 conv as K-split GEMM. grid 256: (type, ic, khh).
// 512 thr, lane = il (output pos), wave = oc-eighth. No LDS, no barriers.
__global__ __launch_bounds__(512) void k2(const float* __restrict__ ws_qP,
                                          const float* __restrict__ ws_kP,
                                          const float* __restrict__ wq,
                                          const float* __restrict__ wk,
                                          float* __restrict__ part)
{
    const int b = blockIdx.x, t = threadIdx.x;
    const int type = b >> 7, ic = (b >> 1) & 63, khh = b & 1;
    const int kh0 = khh ? 6 : 0, nkh = khh ? 5 : 6;
    const float* plane = (type ? ws_kP : ws_qP) + ic*PL;
    const float* wsrc  = (type ? wk : wq) + ic*121 + kh0*11;
    const int lane = t & 63;
    const int oc0 = __builtin_amdgcn_readfirstlane(t >> 6) * 8;   // wave-uniform
    const int ox = lane >> 3, oy = lane & 7;

    float acc[8] = {0.f,0.f,0.f,0.f,0.f,0.f,0.f,0.f};
    #pragma unroll
    for (int khl = 0; khl < 6; ++khl) {
        if (khl < nkh) {
            const int xp = ox*8 + kh0 + khl;
            const float* prow = plane + xp*68 + oy*8;     // 16B-aligned
            const float4 r0 = *(const float4*)(prow);
            const float4 r1 = *(const float4*)(prow + 4);
            const float4 r2 = *(const float4*)(prow + 8);
            const float pr[12] = {r0.x,r0.y,r0.z,r0.w, r1.x,r1.y,r1.z,r1.w,
                                  r2.x,r2.y,r2.z,r2.w};
            const float* wrow = wsrc + khl*11;
            #pragma unroll
            for (int kw = 0; kw < 11; ++kw) {
                const float pv = pr[kw];
                #pragma unroll
                for (int j = 0; j < 8; ++j) {
                    const float wgt = wrow[(oc0 + j)*7744 + kw];  // uniform -> s_load
                    acc[j] = fmaf(wgt, pv, acc[j]);
                }
            }
        }
    }
    float* pp = part + (size_t)b*4096 + lane;
    #pragma unroll
    for (int j = 0; j < 8; ++j) pp[(oc0 + j)*64] = acc[j];
}

// ---------------- K3: fused reduce(+bias+GELU) + dots + softmax + PV ----------------
// grid 64 = (h = b>>3, xo = b&7). 512 thr.
// Reduce parallelism fixed vs round-10: kd unroll 32 (4 latency batches),
// qd p-split 8-ways across all threads (1 batch) + LDS combine, vr regrouped.
__global__ __launch_bounds__(512) void k3(const float* __restrict__ part,
                                          const float* __restrict__ Vpart,
                                          const float* __restrict__ bq,
                                          const float* __restrict__ bk,
                                          float* __restrict__ out)
{
    __shared__ float kg[520];   // [c][jl] pitch 65
    __shared__ float vr[520];   // [chl][jl] pitch 65
    __shared__ float qg[64];    // [cc][xl]
    __shared__ float red[512];  // qd p-split partials [o][pg]
    const int b = blockIdx.x, t = threadIdx.x;
    const int h = b >> 3, xo = b & 7;
    const int c = t >> 6, jl = t & 63;
    const int oc = h*8 + c;

    // ---- qd partials: thread = (o = t>>3, pg = t&7); 16 loads, 1 latency batch ----
    {
        const int o = t >> 3, pg = t & 7;
        const int qoc = h*8 + (o >> 3);
        const int il = xo*8 + (o & 7);
        const float* pp = part + qoc*64 + il;
        float s0 = 0.f, s1 = 0.f;
        #pragma unroll
        for (int pi = 0; pi < 16; pi += 2) {
            s0 += pp[(size_t)(pg*16 + pi    )*4096];
            s1 += pp[(size_t)(pg*16 + pi + 1)*4096];
        }
        red[o*8 + pg] = s0 + s1;
    }
    // ---- vr slice: thread = (jl = t>>3, chl = t&7); 4 loads ----
    {
        const int vjl = t >> 3, chl = t & 7;
        const int ch = h*8 + chl;
        float s = 0.f;
        #pragma unroll
        for (int p = 0; p < 4; ++p)
            s += Vpart[p*4096 + vjl*64 + ch];
        vr[chl*65 + vjl] = s;
    }
    // ---- kd slice: thread = (c, jl); 128 loads, unroll 32 -> 4 latency batches ----
    {
        const float* pp = part + (size_t)128*4096 + oc*64 + jl;
        float s = 0.f;
        for (int pb = 0; pb < 4; ++pb) {
            float s0 = 0.f, s1 = 0.f;
            #pragma unroll
            for (int pi = 0; pi < 32; pi += 2) {
                s0 += pp[(size_t)(pb*32 + pi    )*4096];
                s1 += pp[(size_t)(pb*32 + pi + 1)*4096];
            }
            s += s0 + s1;
        }
        const float v = s + bk[oc];
        kg[c*65 + jl] = 0.5f*v*(1.0f + erff(v*RSQRT2));
    }
    __syncthreads();
    // ---- qd combine + bias + GELU (one wave) ----
    if (t < 64) {
        float s = 0.f;
        #pragma unroll
        for (int k = 0; k < 8; ++k) s += red[t*8 + k];
        const int qoc = h*8 + (t >> 3);
        const float v = s + bq[qoc];
        qg[t] = 0.5f*v*(1.0f + erff(v*RSQRT2));   // qg[cc*8 + xl]
    }
    __syncthreads();

    // ---- phase B: wave w -> query row x = xo*8 + w; lane = jl ----
    const int w = t >> 6, lane = t & 63;
    float d = 0.f;
    #pragma unroll
    for (int cc = 0; cc < 8; ++cc)
        d = fmaf(qg[cc*8 + w], kg[cc*65 + lane], d);
    d *= SCALE;
    float m = d;
    #pragma unroll
    for (int mm = 1; mm < 64; mm <<= 1) m = fmaxf(m, __shfl_xor(m, mm, 64));
    const float e = __expf(d - m);
    float ssum = e;
    #pragma unroll
    for (int mm = 1; mm < 64; mm <<= 1) ssum += __shfl_xor(ssum, mm, 64);
    const float p = e / ssum;
    const int x = xo*8 + w;
    #pragma unroll
    for (int cc = 0; cc < 8; ++cc) {
        float r = p * vr[cc*65 + lane];
        #pragma unroll
        for (int mm = 1; mm < 64; mm <<= 1) r += __shfl_xor(r, mm, 64);
        out[(h*8 + cc)*4096 + x*64 + lane] = r;
    }
}

extern "C" void kernel_launch(void* const* d_in, const int* in_sizes, int n_in,
                              void* d_out, int out_size, void* d_ws, size_t ws_size,
                              hipStream_t stream) {
    const float* f     = (const float*)d_in[0];
    const float* w_qkv = (const float*)d_in[1];
    const float* wq    = (const float*)d_in[2];
    const float* bq    = (const float*)d_in[3];
    const float* wk    = (const float*)d_in[4];
    const float* bk    = (const float*)d_in[5];
    float* out = (float*)d_out;
    float* ws  = (float*)d_ws;

    k1<<<128, 384, 0, stream>>>(f, w_qkv, ws);
    k2<<<256, 512, 0, stream>>>(ws + QP_OFF, ws + KP_OFF, wq, wk, ws + PART_OFF);
    k3<<<64, 512, 0, stream>>>(ws + PART_OFF, ws + VP_OFF, bq, bk, out);
}

// Round 12
// 27.697 us; speedup vs baseline: 1.6334x; 1.2698x over previous
//
#include <hip/hip_runtime.h>

#define SCALE 0.35355339059327379f   // 8^-0.5
#define RSQRT2 0.70710678118654752f

// ws layout (float offsets)
#define PL      4624                 // 68*68 padded plane
#define QP_OFF  0                    // qP[64 ic][68][68]
#define KP_OFF  (64*PL)
#define PART_OFF (2*64*PL)           // part[256 pid][64 oc][64 il]  (pid = type*128+ic*2+khh)
#define VP_OFF  (PART_OFF + 256*4096)
#define QD_OFF  (VP_OFF + 4*4096)    // qd[oc][il]
#define KD_OFF  (QD_OFF + 4096)
#define VR_OFF  (KD_OFF + 4096)      // Vrow[jl][ch]

// ---------------- K1: 1x1 qkv conv -> planar padded q/k planes + V row-mean partials ----
// grid 128: (x = b>>1, yh = b&1), 384 thr = 6 waves: (type q/k/v) x (y-oct), lane = oc.
__global__ __launch_bounds__(384) void k1(const float* __restrict__ f,
                                          const float* __restrict__ w_qkv,
                                          float* __restrict__ ws)
{
    __shared__ float sm[14656];      // wt[64][193] @0 ; fl[64][36] @12352
    const int b = blockIdx.x, t = threadIdx.x;
    const int x = b >> 1, yh = b & 1;
    float* wt = sm;
    float* fl = sm + 12352;

    // zero pad borders: block (x,0) -> qP plane x ; (x,1) -> kP plane x
    {
        float* plane = ws + (yh ? KP_OFF : QP_OFF) + x*PL;
        for (int j = t; j < 528; j += 384) {
            int idx;
            if (j < 272) {
                const int rp = j / 68, c = j % 68;
                const int row = (rp < 2) ? rp : rp + 64;
                idx = row*68 + c;
            } else {
                const int jj = j - 272;
                const int cp = jj >> 6, r2 = (jj & 63) + 2;
                const int col = (cp < 2) ? cp : cp + 64;
                idx = r2*68 + col;
            }
            plane[idx] = 0.f;
        }
    }
    // stage w_qkv transposed: wt[ic][3*64 oc]
    #pragma unroll
    for (int j = 0; j < 8; ++j) {
        const int idx = t + 384*j;   // float4 idx in [0,3072)
        const float4 v = *(const float4*)(w_qkv + 4*idx);
        const int oc = idx >> 4, ic0 = (4*idx) & 63;
        wt[(ic0+0)*193 + oc] = v.x;
        wt[(ic0+1)*193 + oc] = v.y;
        wt[(ic0+2)*193 + oc] = v.z;
        wt[(ic0+3)*193 + oc] = v.w;
    }
    // stage f slab [64 ic][32 y]
    for (int i = t; i < 512; i += 384) {
        const int ic = i >> 3, p = i & 7;
        *(float4*)&fl[ic*36 + p*4] = *(const float4*)(f + ic*4096 + x*64 + yh*32 + p*4);
    }
    __syncthreads();

    const int w = t >> 6, lane = t & 63;
    const int type = w >> 1, yoct = w & 1;
    float acc[16];
    #pragma unroll
    for (int j = 0; j < 16; ++j) acc[j] = 0.f;
    #pragma unroll 4
    for (int ic = 0; ic < 64; ++ic) {
        const float wv = wt[ic*193 + type*64 + lane];
        const float4 p0 = *(const float4*)&fl[ic*36 + yoct*16];
        const float4 p1 = *(const float4*)&fl[ic*36 + yoct*16 + 4];
        const float4 p2 = *(const float4*)&fl[ic*36 + yoct*16 + 8];
        const float4 p3 = *(const float4*)&fl[ic*36 + yoct*16 + 12];
        acc[0]  = fmaf(wv, p0.x, acc[0]);  acc[1]  = fmaf(wv, p0.y, acc[1]);
        acc[2]  = fmaf(wv, p0.z, acc[2]);  acc[3]  = fmaf(wv, p0.w, acc[3]);
        acc[4]  = fmaf(wv, p1.x, acc[4]);  acc[5]  = fmaf(wv, p1.y, acc[5]);
        acc[6]  = fmaf(wv, p1.z, acc[6]);  acc[7]  = fmaf(wv, p1.w, acc[7]);
        acc[8]  = fmaf(wv, p2.x, acc[8]);  acc[9]  = fmaf(wv, p2.y, acc[9]);
        acc[10] = fmaf(wv, p2.z, acc[10]); acc[11] = fmaf(wv, p2.w, acc[11]);
        acc[12] = fmaf(wv, p3.x, acc[12]); acc[13] = fmaf(wv, p3.y, acc[13]);
        acc[14] = fmaf(wv, p3.z, acc[14]); acc[15] = fmaf(wv, p3.w, acc[15]);
    }
    if (type < 2) {
        float* plane = ws + (type ? KP_OFF : QP_OFF) + lane*PL;
        const int base = (x + 2)*68 + yh*32 + yoct*16 + 2;
        #pragma unroll
        for (int j = 0; j < 8; ++j)
            *(float2*)(plane + base + 2*j) = make_float2(acc[2*j], acc[2*j+1]);
    } else {
        float s = 0.f;
        #pragma unroll
        for (int j = 0; j < 16; ++j) s += acc[j];
        (ws + VP_OFF)[(yh*2 + yoct)*4096 + x*64 + lane] = s * 0.015625f;  // /64 partial
    }
}

// ---------------- K2: 11x11 s8 conv as K-split GEMM. grid 256: (type, ic, khh).
// 512 thr, lane = il (output pos), wave = oc-eighth. No LDS, no barriers.
// Plane window -> registers (L1-shared across waves); weights -> wave-uniform scalar loads.
__global__ __launch_bounds__(512) void k2(const float* __restrict__ ws_qP,
                                          const float* __restrict__ ws_kP,
                                          const float* __restrict__ wq,
                                          const float* __restrict__ wk,
                                          float* __restrict__ part)
{
    const int b = blockIdx.x, t = threadIdx.x;
    const int type = b >> 7, ic = (b >> 1) & 63, khh = b & 1;
    const int kh0 = khh ? 6 : 0, nkh = khh ? 5 : 6;
    const float* plane = (type ? ws_kP : ws_qP) + ic*PL;
    const float* wsrc  = (type ? wk : wq) + ic*121 + kh0*11;
    const int lane = t & 63;
    const int oc0 = __builtin_amdgcn_readfirstlane(t >> 6) * 8;   // wave-uniform
    const int ox = lane >> 3, oy = lane & 7;

    float acc[8] = {0.f,0.f,0.f,0.f,0.f,0.f,0.f,0.f};
    #pragma unroll
    for (int khl = 0; khl < 6; ++khl) {
        if (khl < nkh) {
            const int xp = ox*8 + kh0 + khl;
            const float* prow = plane + xp*68 + oy*8;     // 16B-aligned
            const float4 r0 = *(const float4*)(prow);
            const float4 r1 = *(const float4*)(prow + 4);
            const float4 r2 = *(const float4*)(prow + 8);
            const float pr[12] = {r0.x,r0.y,r0.z,r0.w, r1.x,r1.y,r1.z,r1.w,
                                  r2.x,r2.y,r2.z,r2.w};
            const float* wrow = wsrc + khl*11;
            #pragma unroll
            for (int kw = 0; kw < 11; ++kw) {
                const float pv = pr[kw];
                #pragma unroll
                for (int j = 0; j < 8; ++j) {
                    const float wgt = wrow[(oc0 + j)*7744 + kw];  // uniform -> s_load
                    acc[j] = fmaf(wgt, pv, acc[j]);
                }
            }
        }
    }
    // partial store: part[b][oc][il]   (pid == b by construction)
    float* pp = part + (size_t)b*4096 + lane;
    #pragma unroll
    for (int j = 0; j < 8; ++j) pp[(oc0 + j)*64] = acc[j];
}

// ---------------- K2R: reduce 128 K-partials per output + bias + exact GELU; Vrow finish.
// grid 128: (type, oc), 256 thr.
__global__ __launch_bounds__(256) void k2r(const float* __restrict__ part,
                                           const float* __restrict__ Vpart,
                                           const float* __restrict__ bq,
                                           const float* __restrict__ bk,
                                           float* __restrict__ qd,
                                           float* __restrict__ kd,
                                           float* __restrict__ Vrow)
{
    __shared__ float red[4][64];
    const int b = blockIdx.x, t = threadIdx.x;
    const int type = b >> 6, oc = b & 63;
    const int il = t & 63, q4 = t >> 6;
    float s = 0.f;
    #pragma unroll 8
    for (int p = q4*32; p < q4*32 + 32; ++p)
        s += part[(size_t)(type*128 + p)*4096 + oc*64 + il];
    red[q4][il] = s;
    if (type == 0 && q4 == 1) {       // Vrow: jl = oc, ch = il (independent work)
        float v = 0.f;
        #pragma unroll
        for (int p = 0; p < 4; ++p) v += Vpart[p*4096 + oc*64 + il];
        Vrow[oc*64 + il] = v;
    }
    __syncthreads();
    if (t < 64) {
        const float tot = red[0][t] + red[1][t] + red[2][t] + red[3][t];
        const float v = tot + (type ? bk[oc] : bq[oc]);
        (type ? kd : qd)[oc*64 + t] = 0.5f*v*(1.0f + erff(v*RSQRT2));
    }
}

// ---------------- K3: dots + softmax + PV + broadcast store ----------------
// grid 64 (x = image row), 512 thr: wave = head, lane = jl.
__global__ __launch_bounds__(512) void k3(const float* __restrict__ qd,
                                          const float* __restrict__ kd,
                                          const float* __restrict__ VrowG,
                                          float* __restrict__ out)
{
    __shared__ float vrow[64*65];     // [ch][jl], pitch 65
    const int x = blockIdx.x, t = threadIdx.x;
    for (int idx = t; idx < 4096; idx += 512) {
        const int jl = idx >> 6, ch = idx & 63;
        vrow[ch*65 + jl] = VrowG[idx];
    }
    __syncthreads();
    const int h = t >> 6, lane = t & 63;
    float d = 0.f;
    #pragma unroll
    for (int c = 0; c < 8; ++c)
        d = fmaf(qd[(h*8 + c)*64 + x], kd[(h*8 + c)*64 + lane], d);
    d *= SCALE;
    float m = d;
    #pragma unroll
    for (int mm = 1; mm < 64; mm <<= 1) m = fmaxf(m, __shfl_xor(m, mm, 64));
    const float e = __expf(d - m);
    float ssum = e;
    #pragma unroll
    for (int mm = 1; mm < 64; mm <<= 1) ssum += __shfl_xor(ssum, mm, 64);
    const float p = e / ssum;
    #pragma unroll
    for (int c = 0; c < 8; ++c) {
        float r = p * vrow[(h*8 + c)*65 + lane];
        #pragma unroll
        for (int mm = 1; mm < 64; mm <<= 1) r += __shfl_xor(r, mm, 64);
        out[(h*8 + c)*4096 + x*64 + lane] = r;
    }
}

extern "C" void kernel_launch(void* const* d_in, const int* in_sizes, int n_in,
                              void* d_out, int out_size, void* d_ws, size_t ws_size,
                              hipStream_t stream) {
    const float* f     = (const float*)d_in[0];
    const float* w_qkv = (const float*)d_in[1];
    const float* wq    = (const float*)d_in[2];
    const float* bq    = (const float*)d_in[3];
    const float* wk    = (const float*)d_in[4];
    const float* bk    = (const float*)d_in[5];
    float* out = (float*)d_out;
    float* ws  = (float*)d_ws;

    k1<<<128, 384, 0, stream>>>(f, w_qkv, ws);
    k2<<<256, 512, 0, stream>>>(ws + QP_OFF, ws + KP_OFF, wq, wk, ws + PART_OFF);
    k2r<<<128, 256, 0, stream>>>(ws + PART_OFF, ws + VP_OFF, bq, bk,
                                 ws + QD_OFF, ws + KD_OFF, ws + VR_OFF);
    k3<<<64, 512, 0, stream>>>(ws + QD_OFF, ws + KD_OFF, ws + VR_OFF, out);
}